// Round 13
// baseline (225.350 us; speedup 1.0000x reference)
//
#include <hip/hip_runtime.h>
#include <hip/hip_bf16.h>

// B=2, L=2048, E=1024, H=16, D=64. Inputs fp32-or-bf16 (per-block detected), mask int32.
// ws: (unused)@0 | mbits@64KB (1MB) | qp@2MB | kp@10MB | vpT@18MB | attn_out@26MB
// qp/kp layout: [b, h, l, d] (R3-proven). qp pre-scaled by log2(e)/32.
// R13: cvt_wfc kernel removed — fc stages W from raw Wfc with inline f32->bf16
// conversion (reg-staged, write-late); attn = R9 (proven 57.1us).

#define B_ 2
#define L_ 2048
#define E_ 1024
#define H_ 16
#define D_ 64

typedef __attribute__((ext_vector_type(8))) short s8v;     // 8 bf16
typedef __attribute__((ext_vector_type(4))) float f4v;     // 4 fp32
typedef __attribute__((ext_vector_type(2))) float f2v;     // 2 fp32

__device__ __forceinline__ f4v mfma16(s8v a, s8v b, f4v c) {
    return __builtin_amdgcn_mfma_f32_16x16x32_bf16(a, b, c, 0, 0, 0);
}

__device__ __forceinline__ float fast_exp2(float x) {
    return __builtin_amdgcn_exp2f(x);
}

__device__ __forceinline__ ushort bf16bits(float f) {
    __hip_bfloat16 h = __float2bfloat16(f);
    return *(ushort*)&h;
}

// async global->LDS, 16B/lane; LDS dest = wave-uniform base + lane*16
__device__ __forceinline__ void glds16(const __hip_bfloat16* g, ushort* l) {
    __builtin_amdgcn_global_load_lds(
        (const __attribute__((address_space(1))) void*)g,
        (__attribute__((address_space(3))) void*)l,
        16, 0, 0);
}

__device__ __forceinline__ s8v ld8_dual(const void* p, size_t idx, bool isf32) {
    if (isf32) {
        const float* pf = (const float*)p + idx;
        f4v f0 = *(const f4v*)pf;
        f4v f1 = *(const f4v*)(pf + 4);
        s8v r;
        r[0] = (short)bf16bits(f0[0]); r[1] = (short)bf16bits(f0[1]);
        r[2] = (short)bf16bits(f0[2]); r[3] = (short)bf16bits(f0[3]);
        r[4] = (short)bf16bits(f1[0]); r[5] = (short)bf16bits(f1[1]);
        r[6] = (short)bf16bits(f1[2]); r[7] = (short)bf16bits(f1[3]);
        return r;
    }
    return *(const s8v*)((const __hip_bfloat16*)p + idx);
}

__device__ __forceinline__ s8v ld8_ws(const __hip_bfloat16* p) {
    return *(const s8v*)p;
}

__device__ __forceinline__ s8v u4_to_s8(uint a, uint b, uint c, uint d) {
    union { uint u[4]; s8v v; } x;
    x.u[0] = a; x.u[1] = b; x.u[2] = c; x.u[3] = d;
    return x.v;
}

// cvt 8 fp32 -> 8 bf16 (RNE via v_cvt_pk) and store 16B to LDS
__device__ __forceinline__ void store_cvt8(ushort* dst, f4v a, f4v b) {
    uint d0, d1, d2, d3;
    asm("v_cvt_pk_bf16_f32 %0, %1, %2" : "=v"(d0) : "v"(a[0]), "v"(a[1]));
    asm("v_cvt_pk_bf16_f32 %0, %1, %2" : "=v"(d1) : "v"(a[2]), "v"(a[3]));
    asm("v_cvt_pk_bf16_f32 %0, %1, %2" : "=v"(d2) : "v"(b[0]), "v"(b[1]));
    asm("v_cvt_pk_bf16_f32 %0, %1, %2" : "=v"(d3) : "v"(b[2]), "v"(b[3]));
    *(s8v*)dst = u4_to_s8(d0, d1, d2, d3);
}

// per-block dtype detect: count big-exponent bf16 patterns in leading u16s of q.
// Deterministic (same input, same threshold) -> identical flag in every block.
__device__ __forceinline__ bool block_detect_f32(const void* q_in, int* sflag) {
    if (threadIdx.x == 0) *sflag = 0;
    __syncthreads();
    const ushort* qq = (const ushort*)q_in + (threadIdx.x & 255) * 16;
    int bad = 0;
    #pragma unroll
    for (int i = 0; i < 16; ++i) bad += (((qq[i] >> 7) & 0xFF) >= 0x8E);
    bad += __shfl_xor(bad, 1);
    bad += __shfl_xor(bad, 2);
    bad += __shfl_xor(bad, 4);
    bad += __shfl_xor(bad, 8);
    bad += __shfl_xor(bad, 16);
    bad += __shfl_xor(bad, 32);
    if ((threadIdx.x & 63) == 0 && threadIdx.x < 256) atomicAdd(sflag, bad);
    __syncthreads();
    return *sflag > 100;
}

// ---------------- merged Q/K/V projection + mask pack ----------------------------
// grid (1024, 4): y=0 Q(prescaled)->qp, y=1 K->kp, y=2 V->vpT, y=3 mask bit-pack.
// W (64x64) staged once per block into LDS (bf16, stride-72 pad).
__global__ __launch_bounds__(256) void proj_all_kernel(
    const void* __restrict__ q_in, const void* __restrict__ k_in,
    const void* __restrict__ v_in,
    const void* __restrict__ Wq, const void* __restrict__ Wk,
    const void* __restrict__ Wv,
    const int* __restrict__ mask, unsigned long long* __restrict__ mbits,
    __hip_bfloat16* __restrict__ qp, __hip_bfloat16* __restrict__ kp,
    __hip_bfloat16* __restrict__ vpT)
{
    __shared__ __align__(16) ushort tile[64][72];   // v-path transpose buffer
    __shared__ __align__(16) ushort wlds[64 * 72];  // staged W (bf16)
    __shared__ int sflag;
    const int wave = threadIdx.x >> 6;
    const int lane = threadIdx.x & 63;
    const int quad = lane >> 4;
    const int l16  = lane & 15;

    if (blockIdx.y == 3) {
        // mask -> ballot bits: 128 u64 per block (32 per wave)
        const int lane_ = threadIdx.x & 63;
        const size_t wbase = (size_t)blockIdx.x * 128 + wave * 32;
        #pragma unroll 4
        for (int i = 0; i < 32; ++i) {
            const size_t widx = wbase + i;
            const int v = mask[widx * 64 + lane_];
            const unsigned long long bal = __ballot(v != 0);
            if (lane_ == 0) mbits[widx] = bal;
        }
        return;
    }

    const bool isf32 = block_detect_f32(q_in, &sflag);

    // stage W -> wlds (once per block; 16 elems per thread)
    {
        const void* W = blockIdx.y == 0 ? Wq : (blockIdx.y == 1 ? Wk : Wv);
        const int row = threadIdx.x >> 2;
        const int c0  = (threadIdx.x & 3) * 16;
        if (isf32) {
            const float* wsrc = (const float*)W + row * 64 + c0;
            #pragma unroll
            for (int j = 0; j < 16; ++j)
                wlds[row * 72 + c0 + j] = bf16bits(wsrc[j]);
        } else {
            const ushort* wsrc = (const ushort*)W + row * 64 + c0;
            *(s8v*)&wlds[row * 72 + c0]     = *(const s8v*)wsrc;
            *(s8v*)&wlds[row * 72 + c0 + 8] = *(const s8v*)(wsrc + 8);
        }
    }
    __syncthreads();

    if (blockIdx.y < 2) {
        const void* X = blockIdx.y == 0 ? q_in : k_in;
        __hip_bfloat16* dst = blockIdx.y == 0 ? qp : kp;
        // fold softmax scale (log2e/32) into Q
        const float oscale = (blockIdx.y == 0) ? 0.045084439755930314f : 1.0f;
        const int m0 = (blockIdx.x * 4 + wave) * 16;

        const size_t abase = (size_t)(m0 + l16) * D_;
        s8v a0 = ld8_dual(X, abase + quad * 8, isf32);
        s8v a1 = ld8_dual(X, abase + 32 + quad * 8, isf32);

        f4v acc[4];
        #pragma unroll
        for (int nt = 0; nt < 4; ++nt) {
            const ushort* wr = &wlds[(nt * 16 + l16) * 72];
            s8v b0 = *(const s8v*)(wr + quad * 8);
            s8v b1 = *(const s8v*)(wr + 32 + quad * 8);
            f4v c = {0.f, 0.f, 0.f, 0.f};
            c = mfma16(a0, b0, c);
            c = mfma16(a1, b1, c);
            acc[nt] = c;
        }
        // [b,h,l,d] layout (R3): h = m & 15, flat bl = m >> 4
        #pragma unroll
        for (int r = 0; r < 4; ++r) {
            const int m = m0 + quad * 4 + r;
            const int h = m & 15;
            const int bl = m >> 4;
            const int b = bl >> 11;
            const int l = bl & (L_ - 1);
            #pragma unroll
            for (int nt = 0; nt < 4; ++nt) {
                const int e = nt * 16 + l16;
                dst[(((size_t)(b * H_ + h)) * L_ + l) * D_ + e] =
                    __float2bfloat16(acc[nt][r] * oscale);
            }
        }
    } else {
        // V projection with LDS transpose -> vpT[B,H,D,L]
        const int l0 = (blockIdx.x & 31) * 64;
        const int bh = blockIdx.x >> 5;
        const int b = bh >> 4, h = bh & 15;
        const int lw = l0 + wave * 16;

        const size_t xbase = ((size_t)(b * L_ + lw + l16)) * E_ + h * D_;
        s8v a0 = ld8_dual(v_in, xbase + quad * 8, isf32);
        s8v a1 = ld8_dual(v_in, xbase + 32 + quad * 8, isf32);

        #pragma unroll
        for (int nt = 0; nt < 4; ++nt) {
            const int e = nt * 16 + l16;
            const ushort* wr = &wlds[e * 72];
            s8v b0 = *(const s8v*)(wr + quad * 8);
            s8v b1 = *(const s8v*)(wr + 32 + quad * 8);
            f4v c = {0.f, 0.f, 0.f, 0.f};
            c = mfma16(a0, b0, c);
            c = mfma16(a1, b1, c);
            #pragma unroll
            for (int r = 0; r < 4; ++r)
                tile[wave * 16 + quad * 4 + r][e] = bf16bits(c[r]);
        }
        __syncthreads();
        const int e  = threadIdx.x >> 2;
        const int lc = (threadIdx.x & 3) * 16;
        s8v s0, s1;
        #pragma unroll
        for (int i = 0; i < 8; ++i) {
            s0[i] = (short)tile[lc + i][e];
            s1[i] = (short)tile[lc + 8 + i][e];
        }
        __hip_bfloat16* drow = vpT + ((size_t)bh * D_ + e) * L_ + l0 + lc;
        *(s8v*)drow = s0;
        *(s8v*)(drow + 8) = s1;
    }
}

// ---------------- Flash attention: counted-vmcnt pipeline (R9, proven 57.1us) ----
// 8 waves, 4-buffer LDS rotation, depth-2 prefetch, raw s_barrier with
// asm "s_waitcnt vmcnt(6)": per iter each wave issues exactly 3 vmem ops
// (K glds16, V glds16, mask u64 for tile t+2); vmcnt(6) retires only the oldest
// triple (tile t) and leaves tiles t+1,t+2 in flight across the barrier.
// Hazards: RAW covered by per-wave vmcnt + barrier; WAR (overwrite of
// buf[(t+2)%4], read at t-2) covered by the t-1 barrier. Mask words in 4 named
// registers (x4 unroll -> static indexing). sched_barrier(0) pins ds_reads.
__global__ __launch_bounds__(512, 2) void attn_kernel(
    const __hip_bfloat16* __restrict__ qp,
    const __hip_bfloat16* __restrict__ kp,
    const __hip_bfloat16* __restrict__ vpT,
    const unsigned long long* __restrict__ mbits,   // [B][L][32] u64
    __hip_bfloat16* __restrict__ attn_out)
{
    __shared__ __align__(16) ushort kv[4][2][64 * 64];   // [buf][K/V][tile] 64KB

    const int wave = threadIdx.x >> 6;       // 0..7
    const int lane = threadIdx.x & 63;
    const int quad = lane >> 4;
    const int l16  = lane & 15;
    const int sw   = l16 & 7;
    const int bh = blockIdx.y;
    const int b = bh >> 4, h = bh & 15;
    const int q0 = blockIdx.x * 128 + wave * 16;

    const __hip_bfloat16* kbh = kp + (size_t)bh * L_ * D_;
    const __hip_bfloat16* vbh = vpT + (size_t)bh * D_ * L_;
    // one u64 of mask bits per lane per iter: row = q0 + l16
    const unsigned long long* mrow = mbits + ((size_t)b * L_ + q0 + l16) * 32;

    const int lrow = lane >> 3;
    const int lchk = (lane & 7) ^ lrow;
    const int r0 = wave * 8;                 // 8 staging rows per wave
    const __hip_bfloat16* kg = kbh + (size_t)(r0 + lrow) * D_ + lchk * 8;
    const __hip_bfloat16* vg = vbh + (size_t)(r0 + lrow) * L_ + lchk * 8;

    const __hip_bfloat16* qbase = qp + ((size_t)bh * L_ + q0) * D_;
    s8v qa0 = ld8_ws(qbase + (size_t)l16 * D_ + quad * 8);
    s8v qa1 = ld8_ws(qbase + (size_t)l16 * D_ + 32 + quad * 8);

    f2v rs2 = {0.f, 0.f};
    f4v o[4];
    #pragma unroll
    for (int nt = 0; nt < 4; ++nt) o[nt] = (f4v){0.f, 0.f, 0.f, 0.f};

    // lane-local LDS read bases (ushort indices); everything else is immediate
    const int ro0 = l16 * 64 + ((quad ^ sw) << 3);
    const int ro1 = l16 * 64 + (((quad + 4) ^ sw) << 3);
    const int shq = quad * 4;

    unsigned long long wq0 = 0, wq1 = 0, wq2 = 0, wq3 = 0;

    // prologue: stage tiles 0,1 (triples: K,V,mask each)
    glds16(kg, &kv[0][0][r0 * 64]);
    glds16(vg, &kv[0][1][r0 * 64]);
    wq0 = mrow[0];
    kg += 64 * D_; vg += 64;
    glds16(kg, &kv[1][0][r0 * 64]);
    glds16(vg, &kv[1][1][r0 * 64]);
    wq1 = mrow[1];
    kg += 64 * D_; vg += 64;

#define ATTN_BODY(IT_, CUR_, DST_, PRE_, VMASM_)                               \
    {                                                                          \
        if (PRE_) {                                                            \
            glds16(kg, &kv[DST_][0][r0 * 64]);                                 \
            glds16(vg, &kv[DST_][1][r0 * 64]);                                 \
            wq##DST_ = mrow[(IT_) + 2];                                        \
            kg += 64 * D_; vg += 64;                                           \
        }                                                                      \
        asm volatile(VMASM_ ::: "memory");                                     \
        __builtin_amdgcn_s_barrier();                                          \
        __builtin_amdgcn_sched_barrier(0);                                     \
        const uint wlo_sh = ((uint)wq##CUR_) >> shq;                           \
        const uint whi_sh = ((uint)(wq##CUR_ >> 32)) >> shq;                   \
        f4v s_[4];                                                             \
        __builtin_amdgcn_s_setprio(1);                                         \
        _Pragma("unroll")                                                      \
        for (int nt = 0; nt < 4; ++nt) {                                       \
            s8v kb0 = *(const s8v*)&kv[CUR_][0][nt * 1024 + ro0];              \
            s8v kb1 = *(const s8v*)&kv[CUR_][0][nt * 1024 + ro1];              \
            f4v c = {0.f, 0.f, 0.f, 0.f};                                      \
            c = mfma16(kb0, qa0, c);                                           \
            c = mfma16(kb1, qa1, c);                                           \
            s_[nt] = c;                                                        \
        }                                                                      \
        __builtin_amdgcn_s_setprio(0);                                         \
        uint dw[4][2];                                                         \
        _Pragma("unroll")                                                      \
        for (int nt = 0; nt < 4; ++nt) {                                       \
            const uint hs = (nt & 2) ? whi_sh : wlo_sh;                        \
            float pr[4];                                                       \
            _Pragma("unroll")                                                  \
            for (int r = 0; r < 4; ++r) {                                      \
                const float p = fast_exp2(s_[nt][r]);                          \
                const int m = __builtin_amdgcn_sbfe((int)hs,                   \
                                  ((nt & 1) << 4) + r, 1);                     \
                pr[r] = __uint_as_float(__float_as_uint(p) & (uint)m);         \
            }                                                                  \
            rs2 += (f2v){pr[0], pr[1]};                                        \
            rs2 += (f2v){pr[2], pr[3]};                                        \
            asm("v_cvt_pk_bf16_f32 %0, %1, %2"                                 \
                : "=v"(dw[nt][0]) : "v"(pr[0]), "v"(pr[1]));                   \
            asm("v_cvt_pk_bf16_f32 %0, %1, %2"                                 \
                : "=v"(dw[nt][1]) : "v"(pr[2]), "v"(pr[3]));                   \
        }                                                                      \
        uint w00 = dw[0][0], w10 = dw[1][0];                                   \
        uint w01 = dw[0][1], w11 = dw[1][1];                                   \
        uint w20 = dw[2][0], w30 = dw[3][0];                                   \
        uint w21 = dw[2][1], w31 = dw[3][1];                                   \
        asm("v_permlane32_swap_b32 %0, %1" : "+v"(w00), "+v"(w10));            \
        asm("v_permlane16_swap_b32 %0, %1" : "+v"(w00), "+v"(w10));            \
        asm("v_permlane32_swap_b32 %0, %1" : "+v"(w01), "+v"(w11));            \
        asm("v_permlane16_swap_b32 %0, %1" : "+v"(w01), "+v"(w11));            \
        asm("v_permlane32_swap_b32 %0, %1" : "+v"(w20), "+v"(w30));            \
        asm("v_permlane16_swap_b32 %0, %1" : "+v"(w20), "+v"(w30));            \
        asm("v_permlane32_swap_b32 %0, %1" : "+v"(w21), "+v"(w31));            \
        asm("v_permlane16_swap_b32 %0, %1" : "+v"(w21), "+v"(w31));            \
        s8v pa0 = u4_to_s8(w00, w01, w10, w11);                                \
        s8v pa1 = u4_to_s8(w20, w21, w30, w31);                                \
        __builtin_amdgcn_s_setprio(1);                                         \
        _Pragma("unroll")                                                      \
        for (int nt = 0; nt < 4; ++nt) {                                       \
            s8v vb0 = *(const s8v*)&kv[CUR_][1][nt * 1024 + ro0];              \
            s8v vb1 = *(const s8v*)&kv[CUR_][1][nt * 1024 + ro1];              \
            o[nt] = mfma16(pa0, vb0, o[nt]);                                   \
            o[nt] = mfma16(pa1, vb1, o[nt]);                                   \
        }                                                                      \
        __builtin_amdgcn_s_setprio(0);                                         \
    }

    for (int it4 = 0; it4 < 7; ++it4) {
        const int t = it4 * 4;
        ATTN_BODY(t,     0, 2, true, "s_waitcnt vmcnt(6)")
        ATTN_BODY(t + 1, 1, 3, true, "s_waitcnt vmcnt(6)")
        ATTN_BODY(t + 2, 2, 0, true, "s_waitcnt vmcnt(6)")
        ATTN_BODY(t + 3, 3, 1, true, "s_waitcnt vmcnt(6)")
    }
    ATTN_BODY(28, 0, 2, true,  "s_waitcnt vmcnt(6)")
    ATTN_BODY(29, 1, 3, true,  "s_waitcnt vmcnt(6)")
    ATTN_BODY(30, 2, 0, false, "s_waitcnt vmcnt(3)")
    ATTN_BODY(31, 3, 1, false, "s_waitcnt vmcnt(0)")
#undef ATTN_BODY

    // epilogue: rsum lives per (quad, q=l16) -> reduce across quads, redistribute
    float v = rs2[0] + rs2[1];
    v += __shfl_xor(v, 16, 64);
    v += __shfl_xor(v, 32, 64);       // now every lane holds sum for q = its l16
    #pragma unroll
    for (int r = 0; r < 4; ++r) {
        const int qrow = quad * 4 + r;                       // O-row within wave
        const float li = __shfl(v, qrow, 64);                // from lane with l16==qrow
        const float inv = 1.0f / fmaxf(li, 1e-30f);
        const int row = q0 + qrow;
        #pragma unroll
        for (int nt = 0; nt < 4; ++nt) {
            const int d = nt * 16 + l16;
            attn_out[((size_t)(b * L_ + row)) * E_ + h * D_ + d] =
                __float2bfloat16(o[nt][r] * inv);
        }
    }
}

// ---------------- Output FC: 128x64-tile dbuf GEMM, inline W conversion ----------
// grid (M/128=32, N/64=16) = 512 blocks, 256 threads. Wave (wr,wc) owns 64x32:
// acc[4][2], 16 MFMA/wave/iter. BK=64, dbuf LDS 48KB.
// B-operand staged from RAW Wfc: bf16 input -> glds16 direct; fp32 input ->
// reg-staged (load fp32 at prefetch point, cvt_pk + ds_write AFTER the MFMA
// block, before the barrier — T14 issue-early/write-late). LDS image identical
// to the old wfc_bf copy, so read-side swizzle unchanged. Bias read from raw bfc.
__global__ __launch_bounds__(256, 4) void fc_kernel(
    const __hip_bfloat16* __restrict__ x,
    const void* __restrict__ Wfc,
    const void* __restrict__ bfc,
    void* __restrict__ out, const void* __restrict__ q_in)
{
    __shared__ __align__(16) ushort abuf[2][128 * 64];
    __shared__ __align__(16) ushort bbuf[2][64 * 64];
    __shared__ int sflag;
    const bool isf32 = block_detect_f32(q_in, &sflag);
    const int wave = threadIdx.x >> 6;
    const int lane = threadIdx.x & 63;
    const int quad = lane >> 4;
    const int l16  = lane & 15;
    const int sw   = l16 & 7;
    const int m0 = blockIdx.x * 128;
    const int n0 = blockIdx.y * 64;
    const int wr = wave >> 1;       // 0..1 : 64-row slab
    const int wc = wave & 1;        // 0..1 : 32-col slab

    const int lrow = lane >> 3;
    const int lchk = (lane & 7) ^ lrow;

    // staging: A rounds c=0..3 rows c*32+wave*8+lrow; B rounds c=0..1 same pattern
    const __hip_bfloat16* ag[4];
    #pragma unroll
    for (int c = 0; c < 4; ++c)
        ag[c] = x + (size_t)(m0 + c * 32 + wave * 8 + lrow) * E_ + lchk * 8;
    const __hip_bfloat16* bgh[2];   // bf16-input path
    const float* bgf[2];            // fp32-input path
    #pragma unroll
    for (int c = 0; c < 2; ++c) {
        const size_t roff = (size_t)(n0 + c * 32 + wave * 8 + lrow) * E_ + lchk * 8;
        bgh[c] = (const __hip_bfloat16*)Wfc + roff;
        bgf[c] = (const float*)Wfc + roff;
    }

    f4v acc[4][2];
    #pragma unroll
    for (int fm = 0; fm < 4; ++fm)
        #pragma unroll
        for (int fn = 0; fn < 2; ++fn) acc[fm][fn] = (f4v){0.f, 0.f, 0.f, 0.f};

    #pragma unroll
    for (int c = 0; c < 4; ++c) glds16(ag[c], &abuf[0][(c * 32 + wave * 8) * 64]);
    if (!isf32) {
        #pragma unroll
        for (int c = 0; c < 2; ++c) glds16(bgh[c], &bbuf[0][(c * 32 + wave * 8) * 64]);
    } else {
        #pragma unroll
        for (int c = 0; c < 2; ++c) {
            f4v u0 = *(const f4v*)bgf[c];
            f4v u1 = *(const f4v*)(bgf[c] + 4);
            store_cvt8(&bbuf[0][(c * 32 + wave * 8) * 64 + lane * 8], u0, u1);
        }
    }
    __syncthreads();

    int cur = 0;
    for (int it = 0; it < 16; ++it) {
        f4v pw0[2], pw1[2];
        if (it < 15) {
            #pragma unroll
            for (int c = 0; c < 4; ++c)
                glds16(ag[c] + (it + 1) * 64, &abuf[cur ^ 1][(c * 32 + wave * 8) * 64]);
            if (!isf32) {
                #pragma unroll
                for (int c = 0; c < 2; ++c)
                    glds16(bgh[c] + (it + 1) * 64, &bbuf[cur ^ 1][(c * 32 + wave * 8) * 64]);
            } else {
                // issue-early: fp32 W loads into regs; write-late after MFMA block
                #pragma unroll
                for (int c = 0; c < 2; ++c) {
                    pw0[c] = *(const f4v*)(bgf[c] + (it + 1) * 64);
                    pw1[c] = *(const f4v*)(bgf[c] + (it + 1) * 64 + 4);
                }
            }
        }
        s8v a0[4], a1[4];
        #pragma unroll
        for (int fm = 0; fm < 4; ++fm) {
            const ushort* ar = &abuf[cur][(wr * 64 + fm * 16 + l16) * 64];
            a0[fm] = *(const s8v*)(ar + ((quad ^ sw) << 3));
            a1[fm] = *(const s8v*)(ar + (((quad + 4) ^ sw) << 3));
        }
        #pragma unroll
        for (int fn = 0; fn < 2; ++fn) {
            const ushort* br = &bbuf[cur][(wc * 32 + fn * 16 + l16) * 64];
            s8v b0 = *(const s8v*)(br + ((quad ^ sw) << 3));
            s8v b1 = *(const s8v*)(br + (((quad + 4) ^ sw) << 3));
            #pragma unroll
            for (int fm = 0; fm < 4; ++fm) {
                acc[fm][fn] = mfma16(a0[fm], b0, acc[fm][fn]);
                acc[fm][fn] = mfma16(a1[fm], b1, acc[fm][fn]);
            }
        }
        if (it < 15 && isf32) {
            // write-late: HBM latency hidden under the MFMA block above
            #pragma unroll
            for (int c = 0; c < 2; ++c)
                store_cvt8(&bbuf[cur ^ 1][(c * 32 + wave * 8) * 64 + lane * 8],
                           pw0[c], pw1[c]);
        }
        __syncthreads();
        cur ^= 1;
    }
    #pragma unroll
    for (int fm = 0; fm < 4; ++fm) {
        #pragma unroll
        for (int r = 0; r < 4; ++r) {
            const int m = m0 + wr * 64 + fm * 16 + quad * 4 + r;
            #pragma unroll
            for (int fn = 0; fn < 2; ++fn) {
                const int n = n0 + wc * 32 + fn * 16 + l16;
                const float bias = isf32
                    ? ((const float*)bfc)[n]
                    : __bfloat162float(((const __hip_bfloat16*)bfc)[n]);
                const float val = acc[fm][fn][r] + bias;
                if (isf32) ((float*)out)[(size_t)m * E_ + n] = val;
                else       ((__hip_bfloat16*)out)[(size_t)m * E_ + n] = __float2bfloat16(val);
            }
        }
    }
}

extern "C" void kernel_launch(void* const* d_in, const int* in_sizes, int n_in,
                              void* d_out, int out_size, void* d_ws, size_t ws_size,
                              hipStream_t stream) {
    const void* query = d_in[0];
    const void* value = d_in[1];
    const void* key   = d_in[2];
    const int*  mask  = (const int*)d_in[3];
    const void* Wq  = d_in[4];
    const void* Wk  = d_in[5];
    const void* Wv  = d_in[6];
    const void* Wfc = d_in[7];
    const void* bfc = d_in[8];

    char* ws = (char*)d_ws;
    unsigned long long* mbits     = (unsigned long long*)(ws + (64u << 10));
    __hip_bfloat16* qp            = (__hip_bfloat16*)(ws + (2u  << 20));
    __hip_bfloat16* kp            = (__hip_bfloat16*)(ws + (10u << 20));
    __hip_bfloat16* vpT           = (__hip_bfloat16*)(ws + (18u << 20));
    __hip_bfloat16* attn_out      = (__hip_bfloat16*)(ws + (26u << 20));

    proj_all_kernel<<<dim3(1024, 4), 256, 0, stream>>>(
        query, key, value, Wq, Wk, Wv, mask, mbits, qp, kp, vpT);
    attn_kernel<<<dim3(16, 32), 512, 0, stream>>>(qp, kp, vpT, mbits, attn_out);
    fc_kernel<<<dim3(32, 16), 256, 0, stream>>>(attn_out, Wfc, bfc, d_out, query);
}

// Round 14
// 211.272 us; speedup vs baseline: 1.0666x; 1.0666x over previous
//
#include <hip/hip_runtime.h>
#include <hip/hip_bf16.h>

// B=2, L=2048, E=1024, H=16, D=64. Inputs fp32-or-bf16 (per-block detected), mask int32.
// ws: (unused)@0 | mbits@64KB (1MB) | qp@2MB | kp@10MB | vpT@18MB | attn_out@26MB
//     | wfc_bf@34MB (if ws allows; else reuses qp after attn)
// qp/kp layout: [b, h, l, d] (R3-proven). qp pre-scaled by log2(e)/32.
// R14 == R9 (best measured: total 215.0us, attn 57.1us).

#define B_ 2
#define L_ 2048
#define E_ 1024
#define H_ 16
#define D_ 64

typedef __attribute__((ext_vector_type(8))) short s8v;     // 8 bf16
typedef __attribute__((ext_vector_type(4))) float f4v;     // 4 fp32
typedef __attribute__((ext_vector_type(2))) float f2v;     // 2 fp32

__device__ __forceinline__ f4v mfma16(s8v a, s8v b, f4v c) {
    return __builtin_amdgcn_mfma_f32_16x16x32_bf16(a, b, c, 0, 0, 0);
}

__device__ __forceinline__ float fast_exp2(float x) {
    return __builtin_amdgcn_exp2f(x);
}

__device__ __forceinline__ ushort bf16bits(float f) {
    __hip_bfloat16 h = __float2bfloat16(f);
    return *(ushort*)&h;
}

// async global->LDS, 16B/lane; LDS dest = wave-uniform base + lane*16
__device__ __forceinline__ void glds16(const __hip_bfloat16* g, ushort* l) {
    __builtin_amdgcn_global_load_lds(
        (const __attribute__((address_space(1))) void*)g,
        (__attribute__((address_space(3))) void*)l,
        16, 0, 0);
}

__device__ __forceinline__ s8v ld8_dual(const void* p, size_t idx, bool isf32) {
    if (isf32) {
        const float* pf = (const float*)p + idx;
        f4v f0 = *(const f4v*)pf;
        f4v f1 = *(const f4v*)(pf + 4);
        s8v r;
        r[0] = (short)bf16bits(f0[0]); r[1] = (short)bf16bits(f0[1]);
        r[2] = (short)bf16bits(f0[2]); r[3] = (short)bf16bits(f0[3]);
        r[4] = (short)bf16bits(f1[0]); r[5] = (short)bf16bits(f1[1]);
        r[6] = (short)bf16bits(f1[2]); r[7] = (short)bf16bits(f1[3]);
        return r;
    }
    return *(const s8v*)((const __hip_bfloat16*)p + idx);
}

__device__ __forceinline__ s8v ld8_ws(const __hip_bfloat16* p) {
    return *(const s8v*)p;
}

__device__ __forceinline__ s8v u4_to_s8(uint a, uint b, uint c, uint d) {
    union { uint u[4]; s8v v; } x;
    x.u[0] = a; x.u[1] = b; x.u[2] = c; x.u[3] = d;
    return x.v;
}

// per-block dtype detect: count big-exponent bf16 patterns in leading u16s of q.
// Deterministic (same input, same threshold) -> identical flag in every block.
__device__ __forceinline__ bool block_detect_f32(const void* q_in, int* sflag) {
    if (threadIdx.x == 0) *sflag = 0;
    __syncthreads();
    const ushort* qq = (const ushort*)q_in + (threadIdx.x & 255) * 16;
    int bad = 0;
    #pragma unroll
    for (int i = 0; i < 16; ++i) bad += (((qq[i] >> 7) & 0xFF) >= 0x8E);
    bad += __shfl_xor(bad, 1);
    bad += __shfl_xor(bad, 2);
    bad += __shfl_xor(bad, 4);
    bad += __shfl_xor(bad, 8);
    bad += __shfl_xor(bad, 16);
    bad += __shfl_xor(bad, 32);
    if ((threadIdx.x & 63) == 0 && threadIdx.x < 256) atomicAdd(sflag, bad);
    __syncthreads();
    return *sflag > 100;
}

// convert 4 elements of Wfc/bfc (flat index i4*4) into bf16 staging buffers
__device__ __forceinline__ void cvt_piece(
    size_t i4, const void* Wfc, const void* bfc,
    __hip_bfloat16* wfc_bf, __hip_bfloat16* bfc_bf, bool isf32)
{
    const size_t base = i4 * 4;
    const size_t n1 = (size_t)E_ * E_;
    if (base >= n1 + E_) return;
    const void* src = (base < n1) ? Wfc : bfc;
    const size_t off = (base < n1) ? base : base - n1;
    __hip_bfloat16* dst = (base < n1) ? (wfc_bf + off) : (bfc_bf + off);
    if (isf32) {
        f4v v = *(const f4v*)((const float*)src + off);
        #pragma unroll
        for (int j = 0; j < 4; ++j) dst[j] = __float2bfloat16(v[j]);
    } else {
        *(ushort4*)dst = *(const ushort4*)((const ushort*)src + off);
    }
}

// ---------------- merged Q/K/V projection + mask pack (+ optional Wfc cvt) --------
// grid (1024, ny): y=0 Q(prescaled)->qp, y=1 K->kp, y=2 V->vpT,
//                  y=3 mask bit-pack, y=4 (if present) Wfc/bfc -> bf16
// W (64x64) staged once per block into LDS (bf16, stride-72 pad).
__global__ __launch_bounds__(256) void proj_all_kernel(
    const void* __restrict__ q_in, const void* __restrict__ k_in,
    const void* __restrict__ v_in,
    const void* __restrict__ Wq, const void* __restrict__ Wk,
    const void* __restrict__ Wv,
    const void* __restrict__ Wfc, const void* __restrict__ bfc,
    const int* __restrict__ mask, unsigned long long* __restrict__ mbits,
    __hip_bfloat16* __restrict__ qp, __hip_bfloat16* __restrict__ kp,
    __hip_bfloat16* __restrict__ vpT,
    __hip_bfloat16* __restrict__ wfc_bf, __hip_bfloat16* __restrict__ bfc_bf)
{
    __shared__ __align__(16) ushort tile[64][72];   // v-path transpose buffer
    __shared__ __align__(16) ushort wlds[64 * 72];  // staged W (bf16)
    __shared__ int sflag;
    const int wave = threadIdx.x >> 6;
    const int lane = threadIdx.x & 63;
    const int quad = lane >> 4;
    const int l16  = lane & 15;

    if (blockIdx.y == 3) {
        // mask -> ballot bits: 128 u64 per block (32 per wave)
        const int lane_ = threadIdx.x & 63;
        const size_t wbase = (size_t)blockIdx.x * 128 + wave * 32;
        #pragma unroll 4
        for (int i = 0; i < 32; ++i) {
            const size_t widx = wbase + i;
            const int v = mask[widx * 64 + lane_];
            const unsigned long long bal = __ballot(v != 0);
            if (lane_ == 0) mbits[widx] = bal;
        }
        return;
    }

    const bool isf32 = block_detect_f32(q_in, &sflag);

    if (blockIdx.y == 4) {
        cvt_piece((size_t)blockIdx.x * 256 + threadIdx.x, Wfc, bfc, wfc_bf, bfc_bf, isf32);
        if (blockIdx.x == 0)
            cvt_piece((size_t)(E_ * (size_t)E_ / 4) + threadIdx.x, Wfc, bfc, wfc_bf, bfc_bf, isf32);
        return;
    }

    // stage W -> wlds (once per block; 16 elems per thread)
    {
        const void* W = blockIdx.y == 0 ? Wq : (blockIdx.y == 1 ? Wk : Wv);
        const int row = threadIdx.x >> 2;
        const int c0  = (threadIdx.x & 3) * 16;
        if (isf32) {
            const float* wsrc = (const float*)W + row * 64 + c0;
            #pragma unroll
            for (int j = 0; j < 16; ++j)
                wlds[row * 72 + c0 + j] = bf16bits(wsrc[j]);
        } else {
            const ushort* wsrc = (const ushort*)W + row * 64 + c0;
            *(s8v*)&wlds[row * 72 + c0]     = *(const s8v*)wsrc;
            *(s8v*)&wlds[row * 72 + c0 + 8] = *(const s8v*)(wsrc + 8);
        }
    }
    __syncthreads();

    if (blockIdx.y < 2) {
        const void* X = blockIdx.y == 0 ? q_in : k_in;
        __hip_bfloat16* dst = blockIdx.y == 0 ? qp : kp;
        // fold softmax scale (log2e/32) into Q
        const float oscale = (blockIdx.y == 0) ? 0.045084439755930314f : 1.0f;
        const int m0 = (blockIdx.x * 4 + wave) * 16;

        const size_t abase = (size_t)(m0 + l16) * D_;
        s8v a0 = ld8_dual(X, abase + quad * 8, isf32);
        s8v a1 = ld8_dual(X, abase + 32 + quad * 8, isf32);

        f4v acc[4];
        #pragma unroll
        for (int nt = 0; nt < 4; ++nt) {
            const ushort* wr = &wlds[(nt * 16 + l16) * 72];
            s8v b0 = *(const s8v*)(wr + quad * 8);
            s8v b1 = *(const s8v*)(wr + 32 + quad * 8);
            f4v c = {0.f, 0.f, 0.f, 0.f};
            c = mfma16(a0, b0, c);
            c = mfma16(a1, b1, c);
            acc[nt] = c;
        }
        // [b,h,l,d] layout (R3): h = m & 15, flat bl = m >> 4
        #pragma unroll
        for (int r = 0; r < 4; ++r) {
            const int m = m0 + quad * 4 + r;
            const int h = m & 15;
            const int bl = m >> 4;
            const int b = bl >> 11;
            const int l = bl & (L_ - 1);
            #pragma unroll
            for (int nt = 0; nt < 4; ++nt) {
                const int e = nt * 16 + l16;
                dst[(((size_t)(b * H_ + h)) * L_ + l) * D_ + e] =
                    __float2bfloat16(acc[nt][r] * oscale);
            }
        }
    } else {
        // V projection with LDS transpose -> vpT[B,H,D,L]
        const int l0 = (blockIdx.x & 31) * 64;
        const int bh = blockIdx.x >> 5;
        const int b = bh >> 4, h = bh & 15;
        const int lw = l0 + wave * 16;

        const size_t xbase = ((size_t)(b * L_ + lw + l16)) * E_ + h * D_;
        s8v a0 = ld8_dual(v_in, xbase + quad * 8, isf32);
        s8v a1 = ld8_dual(v_in, xbase + 32 + quad * 8, isf32);

        #pragma unroll
        for (int nt = 0; nt < 4; ++nt) {
            const int e = nt * 16 + l16;
            const ushort* wr = &wlds[e * 72];
            s8v b0 = *(const s8v*)(wr + quad * 8);
            s8v b1 = *(const s8v*)(wr + 32 + quad * 8);
            f4v c = {0.f, 0.f, 0.f, 0.f};
            c = mfma16(a0, b0, c);
            c = mfma16(a1, b1, c);
            #pragma unroll
            for (int r = 0; r < 4; ++r)
                tile[wave * 16 + quad * 4 + r][e] = bf16bits(c[r]);
        }
        __syncthreads();
        const int e  = threadIdx.x >> 2;
        const int lc = (threadIdx.x & 3) * 16;
        s8v s0, s1;
        #pragma unroll
        for (int i = 0; i < 8; ++i) {
            s0[i] = (short)tile[lc + i][e];
            s1[i] = (short)tile[lc + 8 + i][e];
        }
        __hip_bfloat16* drow = vpT + ((size_t)bh * D_ + e) * L_ + l0 + lc;
        *(s8v*)drow = s0;
        *(s8v*)(drow + 8) = s1;
    }
}

// ---------------- standalone Wfc cvt (fallback when ws is tight; after attn) ------
__global__ __launch_bounds__(256) void cvt_wfc_kernel(
    const void* __restrict__ Wfc, const void* __restrict__ bfc,
    __hip_bfloat16* __restrict__ wfc_bf, __hip_bfloat16* __restrict__ bfc_bf,
    const void* __restrict__ q_in)
{
    __shared__ int sflag;
    const bool isf32 = block_detect_f32(q_in, &sflag);
    cvt_piece((size_t)blockIdx.x * 256 + threadIdx.x, Wfc, bfc, wfc_bf, bfc_bf, isf32);
}

// ---------------- Flash attention: counted-vmcnt pipeline (T4), 8 waves ----------
// 4-buffer LDS rotation, depth-2 prefetch, raw s_barrier with
// asm "s_waitcnt vmcnt(6)" (NOT __syncthreads' vmcnt(0) drain): per iter each
// wave issues exactly 3 vmem ops (K glds16, V glds16, mask u64 for tile t+2);
// vmcnt(6) retires only the oldest triple (tile t) and leaves tiles t+1,t+2 in
// flight across the barrier with ~2 iterations of latency budget.
// Hazards: RAW covered by per-wave vmcnt + barrier; WAR (overwrite of
// buf[(t+2)%4], read at t-2) covered by the t-1 barrier. Mask words in 4 named
// registers (x4 unroll -> static indexing). sched_barrier(0) pins ds_reads
// below the barrier (rule #18).
__global__ __launch_bounds__(512, 2) void attn_kernel(
    const __hip_bfloat16* __restrict__ qp,
    const __hip_bfloat16* __restrict__ kp,
    const __hip_bfloat16* __restrict__ vpT,
    const unsigned long long* __restrict__ mbits,   // [B][L][32] u64
    __hip_bfloat16* __restrict__ attn_out)
{
    __shared__ __align__(16) ushort kv[4][2][64 * 64];   // [buf][K/V][tile] 64KB

    const int wave = threadIdx.x >> 6;       // 0..7
    const int lane = threadIdx.x & 63;
    const int quad = lane >> 4;
    const int l16  = lane & 15;
    const int sw   = l16 & 7;
    const int bh = blockIdx.y;
    const int b = bh >> 4, h = bh & 15;
    const int q0 = blockIdx.x * 128 + wave * 16;

    const __hip_bfloat16* kbh = kp + (size_t)bh * L_ * D_;
    const __hip_bfloat16* vbh = vpT + (size_t)bh * D_ * L_;
    // one u64 of mask bits per lane per iter: row = q0 + l16
    const unsigned long long* mrow = mbits + ((size_t)b * L_ + q0 + l16) * 32;

    const int lrow = lane >> 3;
    const int lchk = (lane & 7) ^ lrow;
    const int r0 = wave * 8;                 // 8 staging rows per wave
    const __hip_bfloat16* kg = kbh + (size_t)(r0 + lrow) * D_ + lchk * 8;
    const __hip_bfloat16* vg = vbh + (size_t)(r0 + lrow) * L_ + lchk * 8;

    const __hip_bfloat16* qbase = qp + ((size_t)bh * L_ + q0) * D_;
    s8v qa0 = ld8_ws(qbase + (size_t)l16 * D_ + quad * 8);
    s8v qa1 = ld8_ws(qbase + (size_t)l16 * D_ + 32 + quad * 8);

    f2v rs2 = {0.f, 0.f};
    f4v o[4];
    #pragma unroll
    for (int nt = 0; nt < 4; ++nt) o[nt] = (f4v){0.f, 0.f, 0.f, 0.f};

    // lane-local LDS read bases (ushort indices); everything else is immediate
    const int ro0 = l16 * 64 + ((quad ^ sw) << 3);
    const int ro1 = l16 * 64 + (((quad + 4) ^ sw) << 3);
    const int shq = quad * 4;

    unsigned long long wq0 = 0, wq1 = 0, wq2 = 0, wq3 = 0;

    // prologue: stage tiles 0,1 (triples: K,V,mask each)
    glds16(kg, &kv[0][0][r0 * 64]);
    glds16(vg, &kv[0][1][r0 * 64]);
    wq0 = mrow[0];
    kg += 64 * D_; vg += 64;
    glds16(kg, &kv[1][0][r0 * 64]);
    glds16(vg, &kv[1][1][r0 * 64]);
    wq1 = mrow[1];
    kg += 64 * D_; vg += 64;

#define ATTN_BODY(IT_, CUR_, DST_, PRE_, VMASM_)                               \
    {                                                                          \
        if (PRE_) {                                                            \
            glds16(kg, &kv[DST_][0][r0 * 64]);                                 \
            glds16(vg, &kv[DST_][1][r0 * 64]);                                 \
            wq##DST_ = mrow[(IT_) + 2];                                        \
            kg += 64 * D_; vg += 64;                                           \
        }                                                                      \
        asm volatile(VMASM_ ::: "memory");                                     \
        __builtin_amdgcn_s_barrier();                                          \
        __builtin_amdgcn_sched_barrier(0);                                     \
        const uint wlo_sh = ((uint)wq##CUR_) >> shq;                           \
        const uint whi_sh = ((uint)(wq##CUR_ >> 32)) >> shq;                   \
        f4v s_[4];                                                             \
        __builtin_amdgcn_s_setprio(1);                                         \
        _Pragma("unroll")                                                      \
        for (int nt = 0; nt < 4; ++nt) {                                       \
            s8v kb0 = *(const s8v*)&kv[CUR_][0][nt * 1024 + ro0];              \
            s8v kb1 = *(const s8v*)&kv[CUR_][0][nt * 1024 + ro1];              \
            f4v c = {0.f, 0.f, 0.f, 0.f};                                      \
            c = mfma16(kb0, qa0, c);                                           \
            c = mfma16(kb1, qa1, c);                                           \
            s_[nt] = c;                                                        \
        }                                                                      \
        __builtin_amdgcn_s_setprio(0);                                         \
        uint dw[4][2];                                                         \
        _Pragma("unroll")                                                      \
        for (int nt = 0; nt < 4; ++nt) {                                       \
            const uint hs = (nt & 2) ? whi_sh : wlo_sh;                        \
            float pr[4];                                                       \
            _Pragma("unroll")                                                  \
            for (int r = 0; r < 4; ++r) {                                      \
                const float p = fast_exp2(s_[nt][r]);                          \
                const int m = __builtin_amdgcn_sbfe((int)hs,                   \
                                  ((nt & 1) << 4) + r, 1);                     \
                pr[r] = __uint_as_float(__float_as_uint(p) & (uint)m);         \
            }                                                                  \
            rs2 += (f2v){pr[0], pr[1]};                                        \
            rs2 += (f2v){pr[2], pr[3]};                                        \
            asm("v_cvt_pk_bf16_f32 %0, %1, %2"                                 \
                : "=v"(dw[nt][0]) : "v"(pr[0]), "v"(pr[1]));                   \
            asm("v_cvt_pk_bf16_f32 %0, %1, %2"                                 \
                : "=v"(dw[nt][1]) : "v"(pr[2]), "v"(pr[3]));                   \
        }                                                                      \
        uint w00 = dw[0][0], w10 = dw[1][0];                                   \
        uint w01 = dw[0][1], w11 = dw[1][1];                                   \
        uint w20 = dw[2][0], w30 = dw[3][0];                                   \
        uint w21 = dw[2][1], w31 = dw[3][1];                                   \
        asm("v_permlane32_swap_b32 %0, %1" : "+v"(w00), "+v"(w10));            \
        asm("v_permlane16_swap_b32 %0, %1" : "+v"(w00), "+v"(w10));            \
        asm("v_permlane32_swap_b32 %0, %1" : "+v"(w01), "+v"(w11));            \
        asm("v_permlane16_swap_b32 %0, %1" : "+v"(w01), "+v"(w11));            \
        asm("v_permlane32_swap_b32 %0, %1" : "+v"(w20), "+v"(w30));            \
        asm("v_permlane16_swap_b32 %0, %1" : "+v"(w20), "+v"(w30));            \
        asm("v_permlane32_swap_b32 %0, %1" : "+v"(w21), "+v"(w31));            \
        asm("v_permlane16_swap_b32 %0, %1" : "+v"(w21), "+v"(w31));            \
        s8v pa0 = u4_to_s8(w00, w01, w10, w11);                                \
        s8v pa1 = u4_to_s8(w20, w21, w30, w31);                                \
        __builtin_amdgcn_s_setprio(1);                                         \
        _Pragma("unroll")                                                      \
        for (int nt = 0; nt < 4; ++nt) {                                       \
            s8v vb0 = *(const s8v*)&kv[CUR_][1][nt * 1024 + ro0];              \
            s8v vb1 = *(const s8v*)&kv[CUR_][1][nt * 1024 + ro1];              \
            o[nt] = mfma16(pa0, vb0, o[nt]);                                   \
            o[nt] = mfma16(pa1, vb1, o[nt]);                                   \
        }                                                                      \
        __builtin_amdgcn_s_setprio(0);                                         \
    }

    for (int it4 = 0; it4 < 7; ++it4) {
        const int t = it4 * 4;
        ATTN_BODY(t,     0, 2, true, "s_waitcnt vmcnt(6)")
        ATTN_BODY(t + 1, 1, 3, true, "s_waitcnt vmcnt(6)")
        ATTN_BODY(t + 2, 2, 0, true, "s_waitcnt vmcnt(6)")
        ATTN_BODY(t + 3, 3, 1, true, "s_waitcnt vmcnt(6)")
    }
    ATTN_BODY(28, 0, 2, true,  "s_waitcnt vmcnt(6)")
    ATTN_BODY(29, 1, 3, true,  "s_waitcnt vmcnt(6)")
    ATTN_BODY(30, 2, 0, false, "s_waitcnt vmcnt(3)")
    ATTN_BODY(31, 3, 1, false, "s_waitcnt vmcnt(0)")
#undef ATTN_BODY

    // epilogue: rsum lives per (quad, q=l16) -> reduce across quads, redistribute
    float v = rs2[0] + rs2[1];
    v += __shfl_xor(v, 16, 64);
    v += __shfl_xor(v, 32, 64);       // now every lane holds sum for q = its l16
    #pragma unroll
    for (int r = 0; r < 4; ++r) {
        const int qrow = quad * 4 + r;                       // O-row within wave
        const float li = __shfl(v, qrow, 64);                // from lane with l16==qrow
        const float inv = 1.0f / fmaxf(li, 1e-30f);
        const int row = q0 + qrow;
        #pragma unroll
        for (int nt = 0; nt < 4; ++nt) {
            const int d = nt * 16 + l16;
            attn_out[((size_t)(b * L_ + row)) * E_ + h * D_ + d] =
                __float2bfloat16(o[nt][r] * inv);
        }
    }
}

// ---------------- Output FC: 128x64-tile dbuf GEMM, 4 waves ----------
// grid (M/128=32, N/64=16) = 512 blocks, 256 threads. Wave (wr,wc) owns 64x32:
// acc[4][2], 16 MFMA/wave/iter. BK=64, dbuf LDS 48KB.
__global__ __launch_bounds__(256, 4) void fc_kernel(
    const __hip_bfloat16* __restrict__ x,
    const __hip_bfloat16* __restrict__ wfc_bf,
    const __hip_bfloat16* __restrict__ bfc_bf,
    void* __restrict__ out, const void* __restrict__ q_in)
{
    __shared__ __align__(16) ushort abuf[2][128 * 64];
    __shared__ __align__(16) ushort bbuf[2][64 * 64];
    __shared__ int sflag;
    const bool isf32 = block_detect_f32(q_in, &sflag);
    const int wave = threadIdx.x >> 6;
    const int lane = threadIdx.x & 63;
    const int quad = lane >> 4;
    const int l16  = lane & 15;
    const int sw   = l16 & 7;
    const int m0 = blockIdx.x * 128;
    const int n0 = blockIdx.y * 64;
    const int wr = wave >> 1;       // 0..1 : 64-row slab
    const int wc = wave & 1;        // 0..1 : 32-col slab

    const int lrow = lane >> 3;
    const int lchk = (lane & 7) ^ lrow;

    // staging: A rounds c=0..3 rows c*32+wave*8+lrow; B rounds c=0..1 same pattern
    const __hip_bfloat16* ag[4];
    #pragma unroll
    for (int c = 0; c < 4; ++c)
        ag[c] = x + (size_t)(m0 + c * 32 + wave * 8 + lrow) * E_ + lchk * 8;
    const __hip_bfloat16* bg[2];
    #pragma unroll
    for (int c = 0; c < 2; ++c)
        bg[c] = wfc_bf + (size_t)(n0 + c * 32 + wave * 8 + lrow) * E_ + lchk * 8;

    f4v acc[4][2];
    #pragma unroll
    for (int fm = 0; fm < 4; ++fm)
        #pragma unroll
        for (int fn = 0; fn < 2; ++fn) acc[fm][fn] = (f4v){0.f, 0.f, 0.f, 0.f};

    #pragma unroll
    for (int c = 0; c < 4; ++c) glds16(ag[c], &abuf[0][(c * 32 + wave * 8) * 64]);
    #pragma unroll
    for (int c = 0; c < 2; ++c) glds16(bg[c], &bbuf[0][(c * 32 + wave * 8) * 64]);
    __syncthreads();

    int cur = 0;
    for (int it = 0; it < 16; ++it) {
        if (it < 15) {
            #pragma unroll
            for (int c = 0; c < 4; ++c)
                glds16(ag[c] + (it + 1) * 64, &abuf[cur ^ 1][(c * 32 + wave * 8) * 64]);
            #pragma unroll
            for (int c = 0; c < 2; ++c)
                glds16(bg[c] + (it + 1) * 64, &bbuf[cur ^ 1][(c * 32 + wave * 8) * 64]);
        }
        s8v a0[4], a1[4];
        #pragma unroll
        for (int fm = 0; fm < 4; ++fm) {
            const ushort* ar = &abuf[cur][(wr * 64 + fm * 16 + l16) * 64];
            a0[fm] = *(const s8v*)(ar + ((quad ^ sw) << 3));
            a1[fm] = *(const s8v*)(ar + (((quad + 4) ^ sw) << 3));
        }
        #pragma unroll
        for (int fn = 0; fn < 2; ++fn) {
            const ushort* br = &bbuf[cur][(wc * 32 + fn * 16 + l16) * 64];
            s8v b0 = *(const s8v*)(br + ((quad ^ sw) << 3));
            s8v b1 = *(const s8v*)(br + (((quad + 4) ^ sw) << 3));
            #pragma unroll
            for (int fm = 0; fm < 4; ++fm) {
                acc[fm][fn] = mfma16(a0[fm], b0, acc[fm][fn]);
                acc[fm][fn] = mfma16(a1[fm], b1, acc[fm][fn]);
            }
        }
        __syncthreads();
        cur ^= 1;
    }
    #pragma unroll
    for (int fm = 0; fm < 4; ++fm) {
        #pragma unroll
        for (int r = 0; r < 4; ++r) {
            const int m = m0 + wr * 64 + fm * 16 + quad * 4 + r;
            #pragma unroll
            for (int fn = 0; fn < 2; ++fn) {
                const int n = n0 + wc * 32 + fn * 16 + l16;
                const float val = acc[fm][fn][r] + __bfloat162float(bfc_bf[n]);
                if (isf32) ((float*)out)[(size_t)m * E_ + n] = val;
                else       ((__hip_bfloat16*)out)[(size_t)m * E_ + n] = __float2bfloat16(val);
            }
        }
    }
}

extern "C" void kernel_launch(void* const* d_in, const int* in_sizes, int n_in,
                              void* d_out, int out_size, void* d_ws, size_t ws_size,
                              hipStream_t stream) {
    const void* query = d_in[0];
    const void* value = d_in[1];
    const void* key   = d_in[2];
    const int*  mask  = (const int*)d_in[3];
    const void* Wq  = d_in[4];
    const void* Wk  = d_in[5];
    const void* Wv  = d_in[6];
    const void* Wfc = d_in[7];
    const void* bfc = d_in[8];

    char* ws = (char*)d_ws;
    unsigned long long* mbits     = (unsigned long long*)(ws + (64u << 10));
    __hip_bfloat16* qp            = (__hip_bfloat16*)(ws + (2u  << 20));
    __hip_bfloat16* kp            = (__hip_bfloat16*)(ws + (10u << 20));
    __hip_bfloat16* vpT           = (__hip_bfloat16*)(ws + (18u << 20));
    __hip_bfloat16* attn_out      = (__hip_bfloat16*)(ws + (26u << 20));

    const bool big_ws = ws_size >= (37ull << 20);
    __hip_bfloat16* wfc_bf = big_ws ? (__hip_bfloat16*)(ws + (34ull << 20)) : qp;
    __hip_bfloat16* bfc_bf = wfc_bf + (size_t)E_ * E_;

    proj_all_kernel<<<dim3(1024, big_ws ? 5 : 4), 256, 0, stream>>>(
        query, key, value, Wq, Wk, Wv, Wfc, bfc, mask, mbits,
        qp, kp, vpT, wfc_bf, bfc_bf);
    attn_kernel<<<dim3(16, 32), 512, 0, stream>>>(qp, kp, vpT, mbits, attn_out);
    if (!big_ws)
        cvt_wfc_kernel<<<1025, 256, 0, stream>>>(Wfc, bfc, wfc_bf, bfc_bf, query);
    fc_kernel<<<dim3(32, 16), 256, 0, stream>>>(attn_out, wfc_bf, bfc_bf, d_out, query);
}